// Round 1
// baseline (4960.859 us; speedup 1.0000x reference)
//
#include <hip/hip_runtime.h>
#include <hip/hip_bf16.h>

// Problem constants (fixed by the reference)
constexpr int DM = 768;     // d_model (GEMM K dim)
constexpr int NS = 24576;   // d_sae
constexpr int NB = 8192;    // batch
constexpr int K  = 64;      // top-k

// ---------------- encode GEMM: z[b][s] = sum_k (x[b][k]-b_pre[k]) * We[s][k] + be[s]
// fp32 vector GEMM, 128x128 tile, BK=16, 256 threads, 8x8 micro-tile per thread.
#define BM 128
#define BN 128
#define BK 16

__global__ __launch_bounds__(256) void encode_gemm(
    const float* __restrict__ x, const float* __restrict__ We,
    const float* __restrict__ be, const float* __restrict__ bp,
    float* __restrict__ z)
{
    __shared__ __align__(16) float As[BK][BM + 4];
    __shared__ __align__(16) float Bs[BK][BN + 4];

    const int t  = threadIdx.x;
    const int bm = blockIdx.y * BM;
    const int bn = blockIdx.x * BN;
    const int tm = (t / 16) * 8;   // row offset in tile
    const int tn = (t % 16) * 8;   // col offset in tile

    float acc[8][8] = {};

    for (int k0 = 0; k0 < DM; k0 += BK) {
        // cooperative load: 512 float4 per operand, 2 per thread
        #pragma unroll
        for (int h = 0; h < 2; ++h) {
            const int q  = t + h * 256;
            const int m  = q >> 2;          // 0..127
            const int kq = (q & 3) * 4;     // 0,4,8,12
            const float4 av = *(const float4*)&x[(size_t)(bm + m) * DM + k0 + kq];
            const float4 pv = *(const float4*)&bp[k0 + kq];
            As[kq + 0][m] = av.x - pv.x;
            As[kq + 1][m] = av.y - pv.y;
            As[kq + 2][m] = av.z - pv.z;
            As[kq + 3][m] = av.w - pv.w;
            const float4 bv = *(const float4*)&We[(size_t)(bn + m) * DM + k0 + kq];
            Bs[kq + 0][m] = bv.x;
            Bs[kq + 1][m] = bv.y;
            Bs[kq + 2][m] = bv.z;
            Bs[kq + 3][m] = bv.w;
        }
        __syncthreads();

        #pragma unroll
        for (int kk = 0; kk < BK; ++kk) {
            float a[8], b[8];
            *(float4*)&a[0] = *(const float4*)&As[kk][tm];
            *(float4*)&a[4] = *(const float4*)&As[kk][tm + 4];
            *(float4*)&b[0] = *(const float4*)&Bs[kk][tn];
            *(float4*)&b[4] = *(const float4*)&Bs[kk][tn + 4];
            #pragma unroll
            for (int i = 0; i < 8; ++i)
                #pragma unroll
                for (int j = 0; j < 8; ++j)
                    acc[i][j] = fmaf(a[i], b[j], acc[i][j]);
        }
        __syncthreads();
    }

    // epilogue: + b_enc, coalesced float4 stores (lanes consecutive in n)
    float4 be0 = *(const float4*)&be[bn + tn];
    float4 be1 = *(const float4*)&be[bn + tn + 4];
    #pragma unroll
    for (int i = 0; i < 8; ++i) {
        const size_t rowoff = (size_t)(bm + tm + i) * NS + bn + tn;
        float4 c0, c1;
        c0.x = acc[i][0] + be0.x; c0.y = acc[i][1] + be0.y;
        c0.z = acc[i][2] + be0.z; c0.w = acc[i][3] + be0.w;
        c1.x = acc[i][4] + be1.x; c1.y = acc[i][5] + be1.y;
        c1.z = acc[i][6] + be1.z; c1.w = acc[i][7] + be1.w;
        *(float4*)&z[rowoff]     = c0;
        *(float4*)&z[rowoff + 4] = c1;
    }
}

// ---------------- top-k: exact radix select per row, in-place sparsify
__device__ __forceinline__ unsigned fkey(float f) {
    unsigned u = __float_as_uint(f);
    return (u & 0x80000000u) ? ~u : (u | 0x80000000u);   // monotonic ascending
}

__global__ __launch_bounds__(256) void topk_kernel(
    float* __restrict__ z, float* __restrict__ tv, int* __restrict__ ti)
{
    const int row = blockIdx.x;
    float* zr = z + (size_t)row * NS;
    const int t = threadIdx.x;

    __shared__ unsigned hist[256];
    __shared__ unsigned s_prefix, s_pmask;
    __shared__ int s_need;
    __shared__ int eqidx[128];
    __shared__ int eqcnt, outcnt;
    __shared__ float osv[K];
    __shared__ int   osi[K];

    if (t == 0) { s_prefix = 0u; s_pmask = 0u; s_need = K; eqcnt = 0; outcnt = 0; }
    __syncthreads();

    // 4 radix rounds, MSB first
    for (int shift = 24; shift >= 0; shift -= 8) {
        hist[t] = 0u;
        __syncthreads();
        const unsigned prefix = s_prefix, pmask = s_pmask;
        for (int i = t; i < NS; i += 256) {
            unsigned u = fkey(zr[i]);
            if ((u & pmask) == prefix) atomicAdd(&hist[(u >> shift) & 255u], 1u);
        }
        __syncthreads();
        if (t == 0) {
            int need = s_need;
            unsigned cum = 0; int sel = 0;
            for (int b = 255; b >= 0; --b) {
                if (cum + hist[b] >= (unsigned)need) { sel = b; break; }
                cum += hist[b];
            }
            s_need   = need - (int)cum;          // ties at the selected key still needed
            s_prefix = prefix | ((unsigned)sel << shift);
            s_pmask  = pmask | (0xFFu << shift);
        }
        __syncthreads();
    }

    const unsigned T = s_prefix;
    const int need = s_need;   // number of elements equal to T to take (>=1)

    // collect indices of exact-threshold ties
    for (int i = t; i < NS; i += 256) {
        if (fkey(zr[i]) == T) {
            int p = atomicAdd(&eqcnt, 1);
            if (p < 128) eqidx[p] = i;
        }
    }
    __syncthreads();
    // pick the `need` smallest tie indices (lax.top_k tie-break: lower index first)
    if (t == 0) {
        int n = eqcnt < 128 ? eqcnt : 128;
        int lim = need < n ? need : n;
        for (int a = 0; a < lim; ++a) {
            int mi = a;
            for (int b = a + 1; b < n; ++b) if (eqidx[b] < eqidx[mi]) mi = b;
            int tmp = eqidx[a]; eqidx[a] = eqidx[mi]; eqidx[mi] = tmp;
        }
    }
    __syncthreads();

    // final pass: keep selected, zero the rest; collect (val, idx)
    for (int i = t; i < NS; i += 256) {
        const float v = zr[i];
        const unsigned u = fkey(v);
        bool sel = (u > T);
        if (u == T) {
            for (int a = 0; a < need; ++a) if (eqidx[a] == i) { sel = true; break; }
        }
        if (sel) {
            int p = atomicAdd(&outcnt, 1);
            if (p < K) { osv[p] = v; osi[p] = i; }
        } else {
            zr[i] = 0.0f;
        }
    }
    __syncthreads();

    // deterministic order: rank-sort the K pairs by index, then write out
    if (tv != nullptr && t < K) {
        const int   myi = osi[t];
        const float myv = osv[t];
        int r = 0;
        #pragma unroll 8
        for (int j = 0; j < K; ++j) r += (osi[j] < myi);
        tv[(size_t)row * K + r] = myv;
        ti[(size_t)row * K + r] = myi;
    }
}

// ---------------- W_dec transpose: [768][24576] -> [24576][768]
__global__ __launch_bounds__(256) void transpose_wdec(
    const float* __restrict__ W, float* __restrict__ WT)
{
    __shared__ float tile[32][33];
    const int bx = blockIdx.x * 32;   // s
    const int by = blockIdx.y * 32;   // d
    const int tx = threadIdx.x & 31;
    const int ty = threadIdx.x >> 5;  // 0..7
    #pragma unroll
    for (int r = 0; r < 32; r += 8)
        tile[ty + r][tx] = W[(size_t)(by + ty + r) * NS + bx + tx];
    __syncthreads();
    #pragma unroll
    for (int r = 0; r < 32; r += 8)
        WT[(size_t)(bx + ty + r) * DM + by + tx] = tile[tx][ty + r];
}

// ---------------- sparse decode, transposed weights (coalesced)
__global__ __launch_bounds__(256) void decode_t(
    const float* __restrict__ tv, const int* __restrict__ ti,
    const float* __restrict__ WT, const float* __restrict__ bd,
    float* __restrict__ recon)
{
    const int row = blockIdx.x;
    const int t = threadIdx.x;
    __shared__ float sv[K];
    __shared__ int   si[K];
    if (t < K) { sv[t] = tv[(size_t)row * K + t]; si[t] = ti[(size_t)row * K + t]; }
    __syncthreads();
    float a0 = bd[t], a1 = bd[t + 256], a2 = bd[t + 512];
    #pragma unroll 4
    for (int k = 0; k < K; ++k) {
        const float* wr = WT + (size_t)si[k] * DM;
        const float v = sv[k];
        a0 = fmaf(v, wr[t],       a0);
        a1 = fmaf(v, wr[t + 256], a1);
        a2 = fmaf(v, wr[t + 512], a2);
    }
    float* rr = recon + (size_t)row * DM;
    rr[t] = a0; rr[t + 256] = a1; rr[t + 512] = a2;
}

// ---------------- sparse decode, original weight layout (fallback, uncoalesced)
__global__ __launch_bounds__(256) void decode_nt(
    const float* __restrict__ tv, const int* __restrict__ ti,
    const float* __restrict__ Wd, const float* __restrict__ bd,
    float* __restrict__ recon)
{
    const int row = blockIdx.x;
    const int t = threadIdx.x;
    __shared__ float sv[K];
    __shared__ int   si[K];
    if (t < K) { sv[t] = tv[(size_t)row * K + t]; si[t] = ti[(size_t)row * K + t]; }
    __syncthreads();
    float a0 = bd[t], a1 = bd[t + 256], a2 = bd[t + 512];
    for (int k = 0; k < K; ++k) {
        const float v = sv[k];
        const int s = si[k];
        a0 = fmaf(v, Wd[(size_t)t * NS + s],         a0);
        a1 = fmaf(v, Wd[(size_t)(t + 256) * NS + s], a1);
        a2 = fmaf(v, Wd[(size_t)(t + 512) * NS + s], a2);
    }
    float* rr = recon + (size_t)row * DM;
    rr[t] = a0; rr[t + 256] = a1; rr[t + 512] = a2;
}

// ---------------- fallback decode with no workspace: scan the sparsified row
__global__ __launch_bounds__(256) void decode_scan(
    const float* __restrict__ z, const float* __restrict__ Wd,
    const float* __restrict__ bd, float* __restrict__ recon)
{
    constexpr int CAP = 96;
    const int row = blockIdx.x;
    const int t = threadIdx.x;
    __shared__ float sv[CAP], sv2[CAP];
    __shared__ int   si[CAP], si2[CAP];
    __shared__ int cnt;
    if (t == 0) cnt = 0;
    __syncthreads();
    const float* zr = z + (size_t)row * NS;
    for (int i = t; i < NS; i += 256) {
        float v = zr[i];
        if (v != 0.0f) { int p = atomicAdd(&cnt, 1); if (p < CAP) { sv[p] = v; si[p] = i; } }
    }
    __syncthreads();
    const int n = cnt < CAP ? cnt : CAP;
    if (t < n) {
        int myi = si[t]; int r = 0;
        for (int j = 0; j < n; ++j) r += (si[j] < myi);
        sv2[r] = sv[t]; si2[r] = myi;
    }
    __syncthreads();
    float a0 = bd[t], a1 = bd[t + 256], a2 = bd[t + 512];
    for (int k = 0; k < n; ++k) {
        const float v = sv2[k];
        const int s = si2[k];
        a0 = fmaf(v, Wd[(size_t)t * NS + s],         a0);
        a1 = fmaf(v, Wd[(size_t)(t + 256) * NS + s], a1);
        a2 = fmaf(v, Wd[(size_t)(t + 512) * NS + s], a2);
    }
    float* rr = recon + (size_t)row * DM;
    rr[t] = a0; rr[t + 256] = a1; rr[t + 512] = a2;
}

extern "C" void kernel_launch(void* const* d_in, const int* in_sizes, int n_in,
                              void* d_out, int out_size, void* d_ws, size_t ws_size,
                              hipStream_t stream) {
    const float* x  = (const float*)d_in[0];
    const float* We = (const float*)d_in[1];
    const float* be = (const float*)d_in[2];
    const float* Wd = (const float*)d_in[3];
    const float* bd = (const float*)d_in[4];
    const float* bp = (const float*)d_in[5];

    float* recon = (float*)d_out;                       // [8192][768]
    float* zs    = recon + (size_t)NB * DM;             // [8192][24576]

    const size_t need_small = (size_t)NB * K * 8;                    // tv + ti (4 MB)
    const size_t need_big   = need_small + (size_t)NS * DM * 4;      // + WT (75.5 MB)

    float* tv = (float*)d_ws;
    int*   ti = (int*)((char*)d_ws + (size_t)NB * K * 4);
    float* WT = (float*)((char*)d_ws + need_small);

    // 1) dense encode into the z_sparse output region
    dim3 gg(NS / BN, NB / BM);
    encode_gemm<<<gg, 256, 0, stream>>>(x, We, be, bp, zs);

    if (ws_size >= need_big) {
        transpose_wdec<<<dim3(NS / 32, DM / 32), 256, 0, stream>>>(Wd, WT);
        topk_kernel<<<NB, 256, 0, stream>>>(zs, tv, ti);
        decode_t<<<NB, 256, 0, stream>>>(tv, ti, WT, bd, recon);
    } else if (ws_size >= need_small) {
        topk_kernel<<<NB, 256, 0, stream>>>(zs, tv, ti);
        decode_nt<<<NB, 256, 0, stream>>>(tv, ti, Wd, bd, recon);
    } else {
        topk_kernel<<<NB, 256, 0, stream>>>(zs, nullptr, nullptr);
        decode_scan<<<NB, 256, 0, stream>>>(zs, Wd, bd, recon);
    }
}

// Round 2
// 3499.859 us; speedup vs baseline: 1.4174x; 1.4174x over previous
//
#include <hip/hip_runtime.h>
#include <hip/hip_bf16.h>

// Problem constants (fixed by the reference)
constexpr int DM = 768;     // d_model (GEMM K dim)
constexpr int NS = 24576;   // d_sae
constexpr int NB = 8192;    // batch
constexpr int K  = 64;      // top-k
constexpr int KP = 2304;    // 3*DM: concatenated split-bf16 K

typedef __attribute__((ext_vector_type(8))) short short8v;
typedef __attribute__((ext_vector_type(4))) short short4v;
typedef __attribute__((ext_vector_type(4))) float f32x4;

__device__ __forceinline__ unsigned short f2bf(float f) {
    unsigned u = __float_as_uint(f);
    u += 0x7FFFu + ((u >> 16) & 1u);          // RNE, finite inputs only
    return (unsigned short)(u >> 16);
}
__device__ __forceinline__ float bf2f(unsigned short h) {
    return __uint_as_float(((unsigned)h) << 16);
}

// ============ split-bf16 operand prep ============
// A' row: [ah | ah | al]  (K'=2304), a = x - b_pre
__global__ __launch_bounds__(256) void prep_A(
    const float* __restrict__ x, const float* __restrict__ bp, short* __restrict__ Ap)
{
    const int i = blockIdx.x * 256 + threadIdx.x;   // NB*192 threads, one float4 each
    const int row = i / 192;
    const int c = (i % 192) * 4;
    const float4 xv = *(const float4*)&x[(size_t)row * DM + c];
    const float4 pv = *(const float4*)&bp[c];
    float a[4] = {xv.x - pv.x, xv.y - pv.y, xv.z - pv.z, xv.w - pv.w};
    short4v h, lo;
    #pragma unroll
    for (int j = 0; j < 4; ++j) {
        unsigned short hh = f2bf(a[j]);
        h[j]  = (short)hh;
        lo[j] = (short)f2bf(a[j] - bf2f(hh));
    }
    const size_t base = (size_t)row * KP + c;
    *(short4v*)&Ap[base]          = h;
    *(short4v*)&Ap[base + DM]     = h;
    *(short4v*)&Ap[base + 2 * DM] = lo;
}

// B' row: [bh | bl | bh]  -> products: ah*bh + ah*bl + al*bh
__global__ __launch_bounds__(256) void prep_B(
    const float* __restrict__ We, short* __restrict__ Bp)
{
    const int i = blockIdx.x * 256 + threadIdx.x;   // NS*192 threads
    const int row = i / 192;
    const int c = (i % 192) * 4;
    const float4 wv = *(const float4*)&We[(size_t)row * DM + c];
    float a[4] = {wv.x, wv.y, wv.z, wv.w};
    short4v h, lo;
    #pragma unroll
    for (int j = 0; j < 4; ++j) {
        unsigned short hh = f2bf(a[j]);
        h[j]  = (short)hh;
        lo[j] = (short)f2bf(a[j] - bf2f(hh));
    }
    const size_t base = (size_t)row * KP + c;
    *(short4v*)&Bp[base]          = h;
    *(short4v*)&Bp[base + DM]     = lo;
    *(short4v*)&Bp[base + 2 * DM] = h;
}

// ============ bf16 MFMA encode GEMM (m97-style 128x128, BK=32) ============
__global__ __launch_bounds__(256) void encode_mfma(
    const short* __restrict__ Ap, const short* __restrict__ Bp,
    const float* __restrict__ be, float* __restrict__ z)
{
    __shared__ __align__(16) short Ash[128 * 32];
    __shared__ __align__(16) short Bsh[128 * 32];

    const int t = threadIdx.x;
    const int l = t & 63;
    const int w = t >> 6;           // wave 0..3 -> (wm,wn) in 2x2
    const int wm = w >> 1, wn = w & 1;
    const int bm = blockIdx.y * 128;
    const int bn = blockIdx.x * 128;

    const int srow = l >> 2;        // staging: row within 16-row chunk
    const int scol = (l & 3) * 8;   // staging: bf16 col offset
    const int lr = l & 15;
    const int k8 = (l >> 4) * 8;

    f32x4 acc[4][4];
    #pragma unroll
    for (int m = 0; m < 4; ++m)
        #pragma unroll
        for (int n = 0; n < 4; ++n)
            acc[m][n] = f32x4{0.f, 0.f, 0.f, 0.f};

    for (int ks = 0; ks < KP; ks += 32) {
        __syncthreads();   // previous compute done reading LDS
        #pragma unroll
        for (int h = 0; h < 2; ++h) {
            const int c = w * 2 + h;            // chunk 0..7 (wave-uniform)
            const int row = c * 16 + srow;      // tile row 0..127
            __builtin_amdgcn_global_load_lds(
                (const __attribute__((address_space(1))) void*)(Ap + (size_t)(bm + row) * KP + ks + scol),
                (__attribute__((address_space(3))) void*)(&Ash[c * 512]), 16, 0, 0);
            __builtin_amdgcn_global_load_lds(
                (const __attribute__((address_space(1))) void*)(Bp + (size_t)(bn + row) * KP + ks + scol),
                (__attribute__((address_space(3))) void*)(&Bsh[c * 512]), 16, 0, 0);
        }
        __syncthreads();   // drains vmcnt(0): tiles ready

        short8v a[4], b[4];
        #pragma unroll
        for (int m = 0; m < 4; ++m)
            a[m] = *(const short8v*)&Ash[(wm * 64 + m * 16 + lr) * 32 + k8];
        #pragma unroll
        for (int n = 0; n < 4; ++n)
            b[n] = *(const short8v*)&Bsh[(wn * 64 + n * 16 + lr) * 32 + k8];
        #pragma unroll
        for (int m = 0; m < 4; ++m)
            #pragma unroll
            for (int n = 0; n < 4; ++n)
                acc[m][n] = __builtin_amdgcn_mfma_f32_16x16x32_bf16(a[m], b[n], acc[m][n], 0, 0, 0);
    }

    // epilogue: + b_enc; C/D layout: col = lane&15, row = (lane>>4)*4 + r
    #pragma unroll
    for (int n = 0; n < 4; ++n) {
        const int col = bn + wn * 64 + n * 16 + lr;
        const float bev = be[col];
        #pragma unroll
        for (int m = 0; m < 4; ++m) {
            const int row0 = bm + wm * 64 + m * 16 + (l >> 4) * 4;
            #pragma unroll
            for (int r = 0; r < 4; ++r)
                z[(size_t)(row0 + r) * NS + col] = acc[m][n][r] + bev;
        }
    }
}

// ============ top-k with exact fp32 boundary refinement ============
__device__ __forceinline__ unsigned fkey(float f) {
    unsigned u = __float_as_uint(f);
    return (u & 0x80000000u) ? ~u : (u | 0x80000000u);   // monotonic ascending
}
__device__ __forceinline__ float key2f(unsigned k) {
    unsigned u = (k & 0x80000000u) ? (k & 0x7FFFFFFFu) : ~k;
    return __uint_as_float(u);
}

constexpr int CCAP = 2048;   // compacted top-byte list
constexpr int CAND = 256;    // refinement candidates
#define EPSR 4e-3f           // candidate window; >> 2*max approx-GEMM error (~1e-4)

__global__ __launch_bounds__(256) void topk_refine(
    float* __restrict__ z,
    const float* __restrict__ x, const float* __restrict__ bp,
    const float* __restrict__ We, const float* __restrict__ be,
    float* __restrict__ tv, int* __restrict__ ti)
{
    const int row = blockIdx.x;
    const int t = threadIdx.x;
    const int l = t & 63;
    const int w = t >> 6;
    float* zr = z + (size_t)row * NS;

    __shared__ unsigned hist[256];
    __shared__ unsigned ckey[CCAP];
    __shared__ int      cidx[CCAP];
    __shared__ int      candi[CAND];
    __shared__ float    cex[CAND];
    __shared__ int      selflag[CAND];
    __shared__ int s_ccnt, s_nc, s_need, s_b1;
    __shared__ unsigned s_prefix, s_pmask;

    hist[t] = 0u;
    if (t == 0) { s_ccnt = 0; s_nc = 0; s_need = K; }
    __syncthreads();

    // round 1: histogram of top byte (full scan)
    for (int i = t; i < NS; i += 256)
        atomicAdd(&hist[fkey(zr[i]) >> 24], 1u);
    __syncthreads();
    if (t == 0) {
        int need = K; unsigned cum = 0; int sel = 0;
        for (int b = 255; b >= 0; --b) {
            if (cum + hist[b] >= (unsigned)need) { sel = b; break; }
            cum += hist[b];
        }
        s_b1 = sel;
        s_need = need - (int)cum;
        s_prefix = (unsigned)sel << 24;
        s_pmask = 0xFF000000u;
    }
    __syncthreads();
    const int b1 = s_b1;

    // compact: every element whose top byte >= b1
    for (int i = t; i < NS; i += 256) {
        unsigned u = fkey(zr[i]);
        if ((int)(u >> 24) >= b1) {
            int p = atomicAdd(&s_ccnt, 1);
            if (p < CCAP) { ckey[p] = u; cidx[p] = i; }
        }
    }
    __syncthreads();
    const bool ovf = (s_ccnt > CCAP);
    const int cc = ovf ? CCAP : s_ccnt;

    // rounds 2..4 on the compacted list (or full row on overflow)
    for (int shift = 16; shift >= 0; shift -= 8) {
        hist[t] = 0u;
        __syncthreads();
        const unsigned prefix = s_prefix, pmask = s_pmask;
        if (!ovf) {
            for (int c = t; c < cc; c += 256) {
                unsigned u = ckey[c];
                if ((u & pmask) == prefix) atomicAdd(&hist[(u >> shift) & 255u], 1u);
            }
        } else {
            for (int i = t; i < NS; i += 256) {
                unsigned u = fkey(zr[i]);
                if ((u & pmask) == prefix) atomicAdd(&hist[(u >> shift) & 255u], 1u);
            }
        }
        __syncthreads();
        if (t == 0) {
            int need = s_need; unsigned cum = 0; int sel = 0;
            for (int b = 255; b >= 0; --b) {
                if (cum + hist[b] >= (unsigned)need) { sel = b; break; }
                cum += hist[b];
            }
            s_need = need - (int)cum;
            s_prefix = prefix | ((unsigned)sel << shift);
            s_pmask = pmask | (0xFFu << shift);
        }
        __syncthreads();
    }

    // candidate window: approx z >= T_approx - EPSR
    const float tf = key2f(s_prefix);
    const unsigned ckth = fkey(tf - EPSR);

    if (!ovf) {
        for (int c = t; c < cc; c += 256) {
            if (ckey[c] >= ckth) {
                int p = atomicAdd(&s_nc, 1);
                if (p < CAND) candi[p] = cidx[c];
            }
        }
        if ((int)(ckth >> 24) < b1) {   // window dips below compact range (rare)
            for (int i = t; i < NS; i += 256) {
                unsigned u = fkey(zr[i]);
                if ((int)(u >> 24) < b1 && u >= ckth) {
                    int p = atomicAdd(&s_nc, 1);
                    if (p < CAND) candi[p] = i;
                }
            }
        }
    } else {
        for (int i = t; i < NS; i += 256) {
            if (fkey(zr[i]) >= ckth) {
                int p = atomicAdd(&s_nc, 1);
                if (p < CAND) candi[p] = i;
            }
        }
    }
    __syncthreads();
    const int n = s_nc < CAND ? s_nc : CAND;

    // exact fp32 dot for each candidate (one wave per candidate, round-robin)
    const float* xr = x + (size_t)row * DM;
    for (int c = w; c < n; c += 4) {
        const int s = candi[c];
        const float* wr = We + (size_t)s * DM;
        float acc = 0.f;
        for (int k = l; k < DM; k += 64)
            acc = fmaf(xr[k] - bp[k], wr[k], acc);
        #pragma unroll
        for (int off = 32; off > 0; off >>= 1)
            acc += __shfl_xor(acc, off);
        if (l == 0) cex[c] = acc + be[s];
    }
    __syncthreads();

    // rank candidates by (exact value desc, index asc); keep top-K
    bool sel = false; float myv = 0.f; int myi = -1;
    if (t < n) {
        myv = cex[t]; myi = candi[t];
        int rk = 0;
        for (int j = 0; j < n; ++j) {
            float vj = cex[j];
            rk += (vj > myv) || (vj == myv && candi[j] < myi);
        }
        sel = (rk < K);
    }
    if (t < CAND) selflag[t] = sel ? 1 : 0;
    __syncthreads();
    if (sel) {
        int r2 = 0;   // index-rank among the selected -> deterministic slots
        for (int j = 0; j < n; ++j) r2 += (selflag[j] && candi[j] < myi);
        tv[(size_t)row * K + r2] = myv;
        ti[(size_t)row * K + r2] = myi;
    }
    __syncthreads();

    // rewrite row: zeros everywhere, exact values at selected indices
    const f32x4 zero4 = {0.f, 0.f, 0.f, 0.f};
    f32x4* zr4 = (f32x4*)zr;
    for (int i = t; i < NS / 4; i += 256) zr4[i] = zero4;
    __syncthreads();
    if (sel) zr[myi] = myv;
}

// ============ W_dec transpose: [768][24576] -> [24576][768] ============
__global__ __launch_bounds__(256) void transpose_wdec(
    const float* __restrict__ W, float* __restrict__ WT)
{
    __shared__ float tile[32][33];
    const int bx = blockIdx.x * 32;   // s
    const int by = blockIdx.y * 32;   // d
    const int tx = threadIdx.x & 31;
    const int ty = threadIdx.x >> 5;  // 0..7
    #pragma unroll
    for (int r = 0; r < 32; r += 8)
        tile[ty + r][tx] = W[(size_t)(by + ty + r) * NS + bx + tx];
    __syncthreads();
    #pragma unroll
    for (int r = 0; r < 32; r += 8)
        WT[(size_t)(bx + ty + r) * DM + by + tx] = tile[tx][ty + r];
}

// ============ sparse decode (transposed weights, coalesced) ============
__global__ __launch_bounds__(256) void decode_t(
    const float* __restrict__ tv, const int* __restrict__ ti,
    const float* __restrict__ WT, const float* __restrict__ bd,
    float* __restrict__ recon)
{
    const int row = blockIdx.x;
    const int t = threadIdx.x;
    __shared__ float sv[K];
    __shared__ int   si[K];
    if (t < K) { sv[t] = tv[(size_t)row * K + t]; si[t] = ti[(size_t)row * K + t]; }
    __syncthreads();
    float a0 = bd[t], a1 = bd[t + 256], a2 = bd[t + 512];
    #pragma unroll 4
    for (int k = 0; k < K; ++k) {
        const float* wr = WT + (size_t)si[k] * DM;
        const float v = sv[k];
        a0 = fmaf(v, wr[t],       a0);
        a1 = fmaf(v, wr[t + 256], a1);
        a2 = fmaf(v, wr[t + 512], a2);
    }
    float* rr = recon + (size_t)row * DM;
    rr[t] = a0; rr[t + 256] = a1; rr[t + 512] = a2;
}

// ===================== round-1 fallback path (fp32 vector GEMM) =====================
#define BM 128
#define BN 128
#define BK 16

__global__ __launch_bounds__(256) void encode_gemm(
    const float* __restrict__ x, const float* __restrict__ We,
    const float* __restrict__ be, const float* __restrict__ bp,
    float* __restrict__ z)
{
    __shared__ __align__(16) float As[BK][BM + 4];
    __shared__ __align__(16) float Bs[BK][BN + 4];

    const int t  = threadIdx.x;
    const int bm = blockIdx.y * BM;
    const int bn = blockIdx.x * BN;
    const int tm = (t / 16) * 8;
    const int tn = (t % 16) * 8;

    float acc[8][8] = {};

    for (int k0 = 0; k0 < DM; k0 += BK) {
        #pragma unroll
        for (int h = 0; h < 2; ++h) {
            const int q  = t + h * 256;
            const int m  = q >> 2;
            const int kq = (q & 3) * 4;
            const float4 av = *(const float4*)&x[(size_t)(bm + m) * DM + k0 + kq];
            const float4 pv = *(const float4*)&bp[k0 + kq];
            As[kq + 0][m] = av.x - pv.x;
            As[kq + 1][m] = av.y - pv.y;
            As[kq + 2][m] = av.z - pv.z;
            As[kq + 3][m] = av.w - pv.w;
            const float4 bv = *(const float4*)&We[(size_t)(bn + m) * DM + k0 + kq];
            Bs[kq + 0][m] = bv.x;
            Bs[kq + 1][m] = bv.y;
            Bs[kq + 2][m] = bv.z;
            Bs[kq + 3][m] = bv.w;
        }
        __syncthreads();

        #pragma unroll
        for (int kk = 0; kk < BK; ++kk) {
            float a[8], b[8];
            *(float4*)&a[0] = *(const float4*)&As[kk][tm];
            *(float4*)&a[4] = *(const float4*)&As[kk][tm + 4];
            *(float4*)&b[0] = *(const float4*)&Bs[kk][tn];
            *(float4*)&b[4] = *(const float4*)&Bs[kk][tn + 4];
            #pragma unroll
            for (int i = 0; i < 8; ++i)
                #pragma unroll
                for (int j = 0; j < 8; ++j)
                    acc[i][j] = fmaf(a[i], b[j], acc[i][j]);
        }
        __syncthreads();
    }

    float4 be0 = *(const float4*)&be[bn + tn];
    float4 be1 = *(const float4*)&be[bn + tn + 4];
    #pragma unroll
    for (int i = 0; i < 8; ++i) {
        const size_t rowoff = (size_t)(bm + tm + i) * NS + bn + tn;
        float4 c0, c1;
        c0.x = acc[i][0] + be0.x; c0.y = acc[i][1] + be0.y;
        c0.z = acc[i][2] + be0.z; c0.w = acc[i][3] + be0.w;
        c1.x = acc[i][4] + be1.x; c1.y = acc[i][5] + be1.y;
        c1.z = acc[i][6] + be1.z; c1.w = acc[i][7] + be1.w;
        *(float4*)&z[rowoff]     = c0;
        *(float4*)&z[rowoff + 4] = c1;
    }
}

__global__ __launch_bounds__(256) void topk_kernel(
    float* __restrict__ z, float* __restrict__ tv, int* __restrict__ ti)
{
    const int row = blockIdx.x;
    float* zr = z + (size_t)row * NS;
    const int t = threadIdx.x;

    __shared__ unsigned hist[256];
    __shared__ unsigned s_prefix, s_pmask;
    __shared__ int s_need;
    __shared__ int eqidx[128];
    __shared__ int eqcnt, outcnt;
    __shared__ float osv[K];
    __shared__ int   osi[K];

    if (t == 0) { s_prefix = 0u; s_pmask = 0u; s_need = K; eqcnt = 0; outcnt = 0; }
    __syncthreads();

    for (int shift = 24; shift >= 0; shift -= 8) {
        hist[t] = 0u;
        __syncthreads();
        const unsigned prefix = s_prefix, pmask = s_pmask;
        for (int i = t; i < NS; i += 256) {
            unsigned u = fkey(zr[i]);
            if ((u & pmask) == prefix) atomicAdd(&hist[(u >> shift) & 255u], 1u);
        }
        __syncthreads();
        if (t == 0) {
            int need = s_need;
            unsigned cum = 0; int sel = 0;
            for (int b = 255; b >= 0; --b) {
                if (cum + hist[b] >= (unsigned)need) { sel = b; break; }
                cum += hist[b];
            }
            s_need   = need - (int)cum;
            s_prefix = prefix | ((unsigned)sel << shift);
            s_pmask  = pmask | (0xFFu << shift);
        }
        __syncthreads();
    }

    const unsigned T = s_prefix;
    const int need = s_need;

    for (int i = t; i < NS; i += 256) {
        if (fkey(zr[i]) == T) {
            int p = atomicAdd(&eqcnt, 1);
            if (p < 128) eqidx[p] = i;
        }
    }
    __syncthreads();
    if (t == 0) {
        int nn = eqcnt < 128 ? eqcnt : 128;
        int lim = need < nn ? need : nn;
        for (int a = 0; a < lim; ++a) {
            int mi = a;
            for (int b = a + 1; b < nn; ++b) if (eqidx[b] < eqidx[mi]) mi = b;
            int tmp = eqidx[a]; eqidx[a] = eqidx[mi]; eqidx[mi] = tmp;
        }
    }
    __syncthreads();

    for (int i = t; i < NS; i += 256) {
        const float v = zr[i];
        const unsigned u = fkey(v);
        bool take = (u > T);
        if (u == T) {
            for (int a = 0; a < need; ++a) if (eqidx[a] == i) { take = true; break; }
        }
        if (take) {
            int p = atomicAdd(&outcnt, 1);
            if (p < K) { osv[p] = v; osi[p] = i; }
        } else {
            zr[i] = 0.0f;
        }
    }
    __syncthreads();

    if (tv != nullptr && t < K) {
        const int   myi = osi[t];
        const float myv = osv[t];
        int r = 0;
        #pragma unroll 8
        for (int j = 0; j < K; ++j) r += (osi[j] < myi);
        tv[(size_t)row * K + r] = myv;
        ti[(size_t)row * K + r] = myi;
    }
}

__global__ __launch_bounds__(256) void decode_nt(
    const float* __restrict__ tv, const int* __restrict__ ti,
    const float* __restrict__ Wd, const float* __restrict__ bd,
    float* __restrict__ recon)
{
    const int row = blockIdx.x;
    const int t = threadIdx.x;
    __shared__ float sv[K];
    __shared__ int   si[K];
    if (t < K) { sv[t] = tv[(size_t)row * K + t]; si[t] = ti[(size_t)row * K + t]; }
    __syncthreads();
    float a0 = bd[t], a1 = bd[t + 256], a2 = bd[t + 512];
    for (int k = 0; k < K; ++k) {
        const float v = sv[k];
        const int s = si[k];
        a0 = fmaf(v, Wd[(size_t)t * NS + s],         a0);
        a1 = fmaf(v, Wd[(size_t)(t + 256) * NS + s], a1);
        a2 = fmaf(v, Wd[(size_t)(t + 512) * NS + s], a2);
    }
    float* rr = recon + (size_t)row * DM;
    rr[t] = a0; rr[t + 256] = a1; rr[t + 512] = a2;
}

__global__ __launch_bounds__(256) void decode_scan(
    const float* __restrict__ z, const float* __restrict__ Wd,
    const float* __restrict__ bd, float* __restrict__ recon)
{
    constexpr int CAP = 96;
    const int row = blockIdx.x;
    const int t = threadIdx.x;
    __shared__ float sv[CAP], sv2[CAP];
    __shared__ int   si[CAP], si2[CAP];
    __shared__ int cnt;
    if (t == 0) cnt = 0;
    __syncthreads();
    const float* zr = z + (size_t)row * NS;
    for (int i = t; i < NS; i += 256) {
        float v = zr[i];
        if (v != 0.0f) { int p = atomicAdd(&cnt, 1); if (p < CAP) { sv[p] = v; si[p] = i; } }
    }
    __syncthreads();
    const int n = cnt < CAP ? cnt : CAP;
    if (t < n) {
        int myi = si[t]; int r = 0;
        for (int j = 0; j < n; ++j) r += (si[j] < myi);
        sv2[r] = sv[t]; si2[r] = myi;
    }
    __syncthreads();
    float a0 = bd[t], a1 = bd[t + 256], a2 = bd[t + 512];
    for (int k = 0; k < n; ++k) {
        const float v = sv2[k];
        const int s = si2[k];
        a0 = fmaf(v, Wd[(size_t)t * NS + s],         a0);
        a1 = fmaf(v, Wd[(size_t)(t + 256) * NS + s], a1);
        a2 = fmaf(v, Wd[(size_t)(t + 512) * NS + s], a2);
    }
    float* rr = recon + (size_t)row * DM;
    rr[t] = a0; rr[t + 256] = a1; rr[t + 512] = a2;
}

// ===================== launch =====================
extern "C" void kernel_launch(void* const* d_in, const int* in_sizes, int n_in,
                              void* d_out, int out_size, void* d_ws, size_t ws_size,
                              hipStream_t stream) {
    const float* x  = (const float*)d_in[0];
    const float* We = (const float*)d_in[1];
    const float* be = (const float*)d_in[2];
    const float* Wd = (const float*)d_in[3];
    const float* bd = (const float*)d_in[4];
    const float* bp = (const float*)d_in[5];

    float* recon = (float*)d_out;                       // [8192][768]
    float* zs    = recon + (size_t)NB * DM;             // [8192][24576]

    const size_t szA = (size_t)NB * KP * 2;             // 37,748,736
    const size_t szB = (size_t)NS * KP * 2;             // 113,246,208
    const size_t szTVI = (size_t)NB * K * 8;            // 4 MB
    const size_t need_new = szA + szB + szTVI;          // ~155 MB (WT reuses Ap+Bp space)

    const size_t need_small = szTVI;
    const size_t need_big   = szTVI + (size_t)NS * DM * 4;

    if (ws_size >= need_new) {
        short* Ap = (short*)d_ws;
        short* Bp = (short*)((char*)d_ws + szA);
        float* WT = (float*)d_ws;                                    // reused after GEMM
        float* tv = (float*)((char*)d_ws + szA + szB);
        int*   ti = (int*)((char*)d_ws + szA + szB + (size_t)NB * K * 4);

        prep_A<<<NB * (DM / 4) / 256, 256, 0, stream>>>(x, bp, Ap);
        prep_B<<<NS * (DM / 4) / 256, 256, 0, stream>>>(We, Bp);
        encode_mfma<<<dim3(NS / 128, NB / 128), 256, 0, stream>>>(Ap, Bp, be, zs);
        topk_refine<<<NB, 256, 0, stream>>>(zs, x, bp, We, be, tv, ti);
        transpose_wdec<<<dim3(NS / 32, DM / 32), 256, 0, stream>>>(Wd, WT);
        decode_t<<<NB, 256, 0, stream>>>(tv, ti, WT, bd, recon);
    } else {
        float* tv = (float*)d_ws;
        int*   ti = (int*)((char*)d_ws + (size_t)NB * K * 4);
        float* WT = (float*)((char*)d_ws + need_small);

        dim3 gg(NS / BN, NB / BM);
        encode_gemm<<<gg, 256, 0, stream>>>(x, We, be, bp, zs);

        if (ws_size >= need_big) {
            transpose_wdec<<<dim3(NS / 32, DM / 32), 256, 0, stream>>>(Wd, WT);
            topk_kernel<<<NB, 256, 0, stream>>>(zs, tv, ti);
            decode_t<<<NB, 256, 0, stream>>>(tv, ti, WT, bd, recon);
        } else if (ws_size >= need_small) {
            topk_kernel<<<NB, 256, 0, stream>>>(zs, tv, ti);
            decode_nt<<<NB, 256, 0, stream>>>(tv, ti, Wd, bd, recon);
        } else {
            topk_kernel<<<NB, 256, 0, stream>>>(zs, nullptr, nullptr);
            decode_scan<<<NB, 256, 0, stream>>>(zs, Wd, bd, recon);
        }
    }
}

// Round 3
// 1287.434 us; speedup vs baseline: 3.8533x; 2.7185x over previous
//
#include <hip/hip_runtime.h>
#include <hip/hip_bf16.h>

// Problem constants (fixed by the reference)
constexpr int DM = 768;     // d_model (GEMM K dim)
constexpr int NS = 24576;   // d_sae
constexpr int NB = 8192;    // batch
constexpr int K  = 64;      // top-k

typedef __attribute__((ext_vector_type(8))) short short8v;
typedef __attribute__((ext_vector_type(4))) short short4v;
typedef __attribute__((ext_vector_type(4))) float f32x4;

__device__ __forceinline__ unsigned short f2bf(float f) {
    unsigned u = __float_as_uint(f);
    u += 0x7FFFu + ((u >> 16) & 1u);          // RNE, finite inputs only
    return (unsigned short)(u >> 16);
}

__device__ __forceinline__ unsigned fkey(float f) {
    unsigned u = __float_as_uint(f);
    return (u & 0x80000000u) ? ~u : (u | 0x80000000u);   // monotonic ascending
}
__device__ __forceinline__ float key2f(unsigned k) {
    unsigned u = (k & 0x80000000u) ? (k & 0x7FFFFFFFu) : ~k;
    return __uint_as_float(u);
}

// ============ bf16 operand prep ============
__global__ __launch_bounds__(256) void prep_bfA(
    const float* __restrict__ x, const float* __restrict__ bp, short* __restrict__ Ah)
{
    const int i = blockIdx.x * 256 + threadIdx.x;   // NB*192 threads, one float4 each
    const int row = i / 192;
    const int c = (i % 192) * 4;
    const float4 xv = *(const float4*)&x[(size_t)row * DM + c];
    const float4 pv = *(const float4*)&bp[c];
    float a[4] = {xv.x - pv.x, xv.y - pv.y, xv.z - pv.z, xv.w - pv.w};
    short4v h;
    #pragma unroll
    for (int j = 0; j < 4; ++j) h[j] = (short)f2bf(a[j]);
    *(short4v*)&Ah[(size_t)row * DM + c] = h;
}

__global__ __launch_bounds__(256) void prep_bfB(
    const float* __restrict__ We, short* __restrict__ Bh)
{
    const int i = blockIdx.x * 256 + threadIdx.x;   // NS*192 threads
    const int row = i / 192;
    const int c = (i % 192) * 4;
    const float4 wv = *(const float4*)&We[(size_t)row * DM + c];
    float a[4] = {wv.x, wv.y, wv.z, wv.w};
    short4v h;
    #pragma unroll
    for (int j = 0; j < 4; ++j) h[j] = (short)f2bf(a[j]);
    *(short4v*)&Bh[(size_t)row * DM + c] = h;
}

// ============ bf16 MFMA encode GEMM (m97-style 128x128, BK=32, K=768) ============
__global__ __launch_bounds__(256) void encode_bf16(
    const short* __restrict__ Ah, const short* __restrict__ Bh,
    const float* __restrict__ be, float* __restrict__ z)
{
    __shared__ __align__(16) short Ash[128 * 32];
    __shared__ __align__(16) short Bsh[128 * 32];

    const int t = threadIdx.x;
    const int l = t & 63;
    const int w = t >> 6;           // wave 0..3 -> (wm,wn) in 2x2
    const int wm = w >> 1, wn = w & 1;
    const int bm = blockIdx.y * 128;
    const int bn = blockIdx.x * 128;

    const int srow = l >> 2;        // staging: row within 16-row chunk
    const int scol = (l & 3) * 8;   // staging: bf16 col offset
    const int lr = l & 15;
    const int k8 = (l >> 4) * 8;

    f32x4 acc[4][4];
    #pragma unroll
    for (int m = 0; m < 4; ++m)
        #pragma unroll
        for (int n = 0; n < 4; ++n)
            acc[m][n] = f32x4{0.f, 0.f, 0.f, 0.f};

    for (int ks = 0; ks < DM; ks += 32) {
        __syncthreads();
        #pragma unroll
        for (int h = 0; h < 2; ++h) {
            const int c = w * 2 + h;            // chunk 0..7 (wave-uniform)
            const int row = c * 16 + srow;      // tile row 0..127
            __builtin_amdgcn_global_load_lds(
                (const __attribute__((address_space(1))) void*)(Ah + (size_t)(bm + row) * DM + ks + scol),
                (__attribute__((address_space(3))) void*)(&Ash[c * 512]), 16, 0, 0);
            __builtin_amdgcn_global_load_lds(
                (const __attribute__((address_space(1))) void*)(Bh + (size_t)(bn + row) * DM + ks + scol),
                (__attribute__((address_space(3))) void*)(&Bsh[c * 512]), 16, 0, 0);
        }
        __syncthreads();

        short8v a[4], b[4];
        #pragma unroll
        for (int m = 0; m < 4; ++m)
            a[m] = *(const short8v*)&Ash[(wm * 64 + m * 16 + lr) * 32 + k8];
        #pragma unroll
        for (int n = 0; n < 4; ++n)
            b[n] = *(const short8v*)&Bsh[(wn * 64 + n * 16 + lr) * 32 + k8];
        #pragma unroll
        for (int m = 0; m < 4; ++m)
            #pragma unroll
            for (int n = 0; n < 4; ++n)
                acc[m][n] = __builtin_amdgcn_mfma_f32_16x16x32_bf16(a[m], b[n], acc[m][n], 0, 0, 0);
    }

    // epilogue: + b_enc; C/D layout: col = lane&15, row = (lane>>4)*4 + r
    #pragma unroll
    for (int n = 0; n < 4; ++n) {
        const int col = bn + wn * 64 + n * 16 + lr;
        const float bev = be[col];
        #pragma unroll
        for (int m = 0; m < 4; ++m) {
            const int row0 = bm + wm * 64 + m * 16 + (l >> 4) * 4;
            #pragma unroll
            for (int r = 0; r < 4; ++r)
                z[(size_t)(row0 + r) * NS + col] = acc[m][n][r] + bev;
        }
    }
}

// ============ fast top-k: single scan + LDS radix + boundary-band exact ============
constexpr int CCAP  = 2048;   // compacted list cap
constexpr int BANDC = 256;    // band candidates cap
#define T0F   1.0f            // static compaction pre-threshold (distribution-based; guarded)
#define DELTA 0.015f          // selection uncertainty band (>= 2*max bf16-GEMM error ~4e-3)

__global__ __launch_bounds__(256) void topk_fast(
    float* __restrict__ z,
    const float* __restrict__ x, const float* __restrict__ bp,
    const float* __restrict__ We, const float* __restrict__ be,
    float* __restrict__ tv, int* __restrict__ ti, int* __restrict__ rowflag)
{
    const int row = blockIdx.x;
    const int t = threadIdx.x;
    const int l = t & 63;
    const int w = t >> 6;
    float* zr = z + (size_t)row * NS;

    __shared__ unsigned ckey[CCAP];
    __shared__ int      cidx[CCAP];
    __shared__ unsigned hist[256];
    __shared__ int   bandi[BANDC];
    __shared__ float bexa[BANDC];
    __shared__ int   cini[K];
    __shared__ float cinf[K];
    __shared__ int   seli[K];
    __shared__ float selv[K];
    __shared__ int s_cc, s_cin, s_bc, s_ns, s_selbin, s_neednext;

    if (t == 0) s_cc = 0;
    __syncthreads();

    // single streaming scan, ballot-compacted push of all elements >= T0F
    const f32x4* zr4 = (const f32x4*)zr;
    for (int i = t; i < NS / 4; i += 256) {
        const f32x4 v = zr4[i];
        #pragma unroll
        for (int j = 0; j < 4; ++j) {
            const bool pred = (v[j] >= T0F);
            const unsigned long long m = __ballot(pred);
            if (m) {
                int base = 0;
                if (l == 0) base = atomicAdd(&s_cc, __popcll(m));
                base = __shfl(base, 0);
                if (pred) {
                    const int p = base + __popcll(m & ((1ull << l) - 1ull));
                    if (p < CCAP) { ckey[p] = fkey(v[j]); cidx[p] = i * 4 + j; }
                }
            }
        }
    }
    __syncthreads();
    const int cc = s_cc;
    if (cc < K || cc > CCAP) { if (t == 0) rowflag[row] = 1; return; }

    // exact radix select of the K-th largest key on the compacted list (LDS only)
    unsigned prefix = 0, pmask = 0; int need = K;
    for (int shift = 24; shift >= 0; shift -= 8) {
        hist[t] = 0u;
        __syncthreads();
        for (int c = t; c < cc; c += 256) {
            const unsigned u = ckey[c];
            if ((u & pmask) == prefix) atomicAdd(&hist[(u >> shift) & 255u], 1u);
        }
        __syncthreads();
        // inclusive suffix sum over 256 bins
        for (int off = 1; off < 256; off <<= 1) {
            const unsigned v = (t + off < 256) ? hist[t + off] : 0u;
            __syncthreads();
            hist[t] += v;
            __syncthreads();
        }
        const unsigned incl = hist[t];
        const unsigned excl = (t < 255) ? hist[t + 1] : 0u;
        if (excl < (unsigned)need && (unsigned)need <= incl) {
            s_selbin = t; s_neednext = need - (int)excl;
        }
        __syncthreads();
        prefix |= ((unsigned)s_selbin) << shift;
        pmask  |= 0xFFu << shift;
        need = s_neednext;
        __syncthreads();
    }

    const float Tf = key2f(prefix);
    if (Tf - DELTA < T0F) { if (t == 0) rowflag[row] = 1; return; }   // band dips under compaction threshold
    const unsigned khi = fkey(Tf + DELTA);
    const unsigned klo = fkey(Tf - DELTA);

    if (t == 0) { s_cin = 0; s_bc = 0; s_ns = 0; }
    __syncthreads();
    for (int c = t; c < cc; c += 256) {
        const unsigned u = ckey[c];
        if (u > khi) {                       // certainly in true top-K
            const int p = atomicAdd(&s_cin, 1);
            if (p < K) { cini[p] = cidx[c]; cinf[p] = key2f(u); }
        } else if (u >= klo) {               // boundary band: needs exact comparison
            const int p = atomicAdd(&s_bc, 1);
            if (p < BANDC) bandi[p] = cidx[c];
        }
    }
    __syncthreads();
    const int cin  = s_cin;
    const int bc   = s_bc;
    const int nsel = K - cin;
    if (cin >= K || bc > BANDC || bc < nsel) { if (t == 0) rowflag[row] = 1; return; }

    // exact fp32 dots for band members only (one wave per member, round-robin)
    const float* xr = x + (size_t)row * DM;
    for (int c = w; c < bc; c += 4) {
        const int s = bandi[c];
        const float* wr = We + (size_t)s * DM;
        float acc = 0.f;
        for (int k = l; k < DM; k += 64)
            acc = fmaf(xr[k] - bp[k], wr[k], acc);
        #pragma unroll
        for (int off = 32; off > 0; off >>= 1) acc += __shfl_xor(acc, off);
        if (l == 0) bexa[c] = acc + be[s];
    }
    __syncthreads();

    // band ranking by (exact desc, index asc); take top nsel
    if (t < bc) {
        const float myv = bexa[t];
        const int myi = bandi[t];
        int rk = 0;
        for (int j = 0; j < bc; ++j) {
            const float vj = bexa[j];
            rk += (vj > myv) || (vj == myv && bandi[j] < myi);
        }
        if (rk < nsel) {
            const int p = atomicAdd(&s_ns, 1);
            if (p < K) { seli[p] = myi; selv[p] = myv; }
        }
    }
    if (t < cin) {
        const int p = atomicAdd(&s_ns, 1);
        if (p < K) { seli[p] = cini[t]; selv[p] = cinf[t]; }
    }
    __syncthreads();
    if (s_ns != K) { if (t == 0) rowflag[row] = 1; return; }
    if (t == 0) rowflag[row] = 0;

    // zero-fill row, then scatter selected (slots rank-sorted by index: deterministic)
    const f32x4 zero4 = {0.f, 0.f, 0.f, 0.f};
    f32x4* zw = (f32x4*)zr;
    for (int i = t; i < NS / 4; i += 256) zw[i] = zero4;
    __syncthreads();
    if (t < K) {
        const int   myi = seli[t];
        const float myv = selv[t];
        int r = 0;
        #pragma unroll 8
        for (int j = 0; j < K; ++j) r += (seli[j] < myi);
        zr[myi] = myv;
        tv[(size_t)row * K + r] = myv;
        ti[(size_t)row * K + r] = myi;
    }
}

// ============ fallback top-k (full-row, wide window, exact everywhere) ============
constexpr int FCAP = 2048;
constexpr int CAND = 256;
#define EPSR 0.03f

__global__ __launch_bounds__(256) void topk_fallback(
    float* __restrict__ z,
    const float* __restrict__ x, const float* __restrict__ bp,
    const float* __restrict__ We, const float* __restrict__ be,
    float* __restrict__ tv, int* __restrict__ ti, const int* __restrict__ rowflag)
{
    const int row = blockIdx.x;
    if (rowflag[row] == 0) return;
    const int t = threadIdx.x;
    const int l = t & 63;
    const int w = t >> 6;
    float* zr = z + (size_t)row * NS;

    __shared__ unsigned hist[256];
    __shared__ unsigned ckey[FCAP];
    __shared__ int      cidx[FCAP];
    __shared__ int      candi[CAND];
    __shared__ float    cex[CAND];
    __shared__ int      selflag[CAND];
    __shared__ int s_ccnt, s_nc, s_need, s_b1;
    __shared__ unsigned s_prefix, s_pmask;

    hist[t] = 0u;
    if (t == 0) { s_ccnt = 0; s_nc = 0; s_need = K; }
    __syncthreads();

    for (int i = t; i < NS; i += 256)
        atomicAdd(&hist[fkey(zr[i]) >> 24], 1u);
    __syncthreads();
    if (t == 0) {
        int need = K; unsigned cum = 0; int sel = 0;
        for (int b = 255; b >= 0; --b) {
            if (cum + hist[b] >= (unsigned)need) { sel = b; break; }
            cum += hist[b];
        }
        s_b1 = sel;
        s_need = need - (int)cum;
        s_prefix = (unsigned)sel << 24;
        s_pmask = 0xFF000000u;
    }
    __syncthreads();
    const int b1 = s_b1;

    for (int i = t; i < NS; i += 256) {
        unsigned u = fkey(zr[i]);
        if ((int)(u >> 24) >= b1) {
            int p = atomicAdd(&s_ccnt, 1);
            if (p < FCAP) { ckey[p] = u; cidx[p] = i; }
        }
    }
    __syncthreads();
    const bool ovf = (s_ccnt > FCAP);
    const int cc = ovf ? FCAP : s_ccnt;

    for (int shift = 16; shift >= 0; shift -= 8) {
        hist[t] = 0u;
        __syncthreads();
        const unsigned prefix = s_prefix, pmask = s_pmask;
        if (!ovf) {
            for (int c = t; c < cc; c += 256) {
                unsigned u = ckey[c];
                if ((u & pmask) == prefix) atomicAdd(&hist[(u >> shift) & 255u], 1u);
            }
        } else {
            for (int i = t; i < NS; i += 256) {
                unsigned u = fkey(zr[i]);
                if ((u & pmask) == prefix) atomicAdd(&hist[(u >> shift) & 255u], 1u);
            }
        }
        __syncthreads();
        if (t == 0) {
            int need = s_need; unsigned cum = 0; int sel = 0;
            for (int b = 255; b >= 0; --b) {
                if (cum + hist[b] >= (unsigned)need) { sel = b; break; }
                cum += hist[b];
            }
            s_need = need - (int)cum;
            s_prefix = prefix | ((unsigned)sel << shift);
            s_pmask = pmask | (0xFFu << shift);
        }
        __syncthreads();
    }

    const float tf = key2f(s_prefix);
    const unsigned ckth = fkey(tf - EPSR);

    if (!ovf) {
        for (int c = t; c < cc; c += 256) {
            if (ckey[c] >= ckth) {
                int p = atomicAdd(&s_nc, 1);
                if (p < CAND) candi[p] = cidx[c];
            }
        }
        if ((int)(ckth >> 24) < b1) {
            for (int i = t; i < NS; i += 256) {
                unsigned u = fkey(zr[i]);
                if ((int)(u >> 24) < b1 && u >= ckth) {
                    int p = atomicAdd(&s_nc, 1);
                    if (p < CAND) candi[p] = i;
                }
            }
        }
    } else {
        for (int i = t; i < NS; i += 256) {
            if (fkey(zr[i]) >= ckth) {
                int p = atomicAdd(&s_nc, 1);
                if (p < CAND) candi[p] = i;
            }
        }
    }
    __syncthreads();
    const int n = s_nc < CAND ? s_nc : CAND;

    const float* xr = x + (size_t)row * DM;
    for (int c = w; c < n; c += 4) {
        const int s = candi[c];
        const float* wr = We + (size_t)s * DM;
        float acc = 0.f;
        for (int k = l; k < DM; k += 64)
            acc = fmaf(xr[k] - bp[k], wr[k], acc);
        #pragma unroll
        for (int off = 32; off > 0; off >>= 1)
            acc += __shfl_xor(acc, off);
        if (l == 0) cex[c] = acc + be[s];
    }
    __syncthreads();

    bool sel = false; float myv = 0.f; int myi = -1;
    if (t < n) {
        myv = cex[t]; myi = candi[t];
        int rk = 0;
        for (int j = 0; j < n; ++j) {
            float vj = cex[j];
            rk += (vj > myv) || (vj == myv && candi[j] < myi);
        }
        sel = (rk < K);
    }
    if (t < CAND) selflag[t] = sel ? 1 : 0;
    __syncthreads();

    const f32x4 zero4 = {0.f, 0.f, 0.f, 0.f};
    f32x4* zr4w = (f32x4*)zr;
    for (int i = t; i < NS / 4; i += 256) zr4w[i] = zero4;
    __syncthreads();
    if (sel) {
        int r2 = 0;
        for (int j = 0; j < n; ++j) r2 += (selflag[j] && candi[j] < myi);
        zr[myi] = myv;
        tv[(size_t)row * K + r2] = myv;
        ti[(size_t)row * K + r2] = myi;
    }
}

// ============ W_dec transpose: [768][24576] -> [24576][768] ============
__global__ __launch_bounds__(256) void transpose_wdec(
    const float* __restrict__ W, float* __restrict__ WT)
{
    __shared__ float tile[32][33];
    const int bx = blockIdx.x * 32;   // s
    const int by = blockIdx.y * 32;   // d
    const int tx = threadIdx.x & 31;
    const int ty = threadIdx.x >> 5;  // 0..7
    #pragma unroll
    for (int r = 0; r < 32; r += 8)
        tile[ty + r][tx] = W[(size_t)(by + ty + r) * NS + bx + tx];
    __syncthreads();
    #pragma unroll
    for (int r = 0; r < 32; r += 8)
        WT[(size_t)(bx + ty + r) * DM + by + tx] = tile[tx][ty + r];
}

// ============ sparse decode (transposed weights, coalesced) ============
__global__ __launch_bounds__(256) void decode_t(
    const float* __restrict__ tv, const int* __restrict__ ti,
    const float* __restrict__ WT, const float* __restrict__ bd,
    float* __restrict__ recon)
{
    const int row = blockIdx.x;
    const int t = threadIdx.x;
    __shared__ float sv[K];
    __shared__ int   si[K];
    if (t < K) { sv[t] = tv[(size_t)row * K + t]; si[t] = ti[(size_t)row * K + t]; }
    __syncthreads();
    float a0 = bd[t], a1 = bd[t + 256], a2 = bd[t + 512];
    #pragma unroll 4
    for (int k = 0; k < K; ++k) {
        const float* wr = WT + (size_t)si[k] * DM;
        const float v = sv[k];
        a0 = fmaf(v, wr[t],       a0);
        a1 = fmaf(v, wr[t + 256], a1);
        a2 = fmaf(v, wr[t + 512], a2);
    }
    float* rr = recon + (size_t)row * DM;
    rr[t] = a0; rr[t + 256] = a1; rr[t + 512] = a2;
}

// ===================== fp32 fallback path (small ws; round-1, validated) =====================
#define BM 128
#define BN 128
#define BK 16

__global__ __launch_bounds__(256) void encode_gemm(
    const float* __restrict__ x, const float* __restrict__ We,
    const float* __restrict__ be, const float* __restrict__ bp,
    float* __restrict__ z)
{
    __shared__ __align__(16) float As[BK][BM + 4];
    __shared__ __align__(16) float Bs[BK][BN + 4];

    const int t  = threadIdx.x;
    const int bm = blockIdx.y * BM;
    const int bn = blockIdx.x * BN;
    const int tm = (t / 16) * 8;
    const int tn = (t % 16) * 8;

    float acc[8][8] = {};

    for (int k0 = 0; k0 < DM; k0 += BK) {
        #pragma unroll
        for (int h = 0; h < 2; ++h) {
            const int q  = t + h * 256;
            const int m  = q >> 2;
            const int kq = (q & 3) * 4;
            const float4 av = *(const float4*)&x[(size_t)(bm + m) * DM + k0 + kq];
            const float4 pv = *(const float4*)&bp[k0 + kq];
            As[kq + 0][m] = av.x - pv.x;
            As[kq + 1][m] = av.y - pv.y;
            As[kq + 2][m] = av.z - pv.z;
            As[kq + 3][m] = av.w - pv.w;
            const float4 bv = *(const float4*)&We[(size_t)(bn + m) * DM + k0 + kq];
            Bs[kq + 0][m] = bv.x;
            Bs[kq + 1][m] = bv.y;
            Bs[kq + 2][m] = bv.z;
            Bs[kq + 3][m] = bv.w;
        }
        __syncthreads();

        #pragma unroll
        for (int kk = 0; kk < BK; ++kk) {
            float a[8], b[8];
            *(float4*)&a[0] = *(const float4*)&As[kk][tm];
            *(float4*)&a[4] = *(const float4*)&As[kk][tm + 4];
            *(float4*)&b[0] = *(const float4*)&Bs[kk][tn];
            *(float4*)&b[4] = *(const float4*)&Bs[kk][tn + 4];
            #pragma unroll
            for (int i = 0; i < 8; ++i)
                #pragma unroll
                for (int j = 0; j < 8; ++j)
                    acc[i][j] = fmaf(a[i], b[j], acc[i][j]);
        }
        __syncthreads();
    }

    float4 be0 = *(const float4*)&be[bn + tn];
    float4 be1 = *(const float4*)&be[bn + tn + 4];
    #pragma unroll
    for (int i = 0; i < 8; ++i) {
        const size_t rowoff = (size_t)(bm + tm + i) * NS + bn + tn;
        float4 c0, c1;
        c0.x = acc[i][0] + be0.x; c0.y = acc[i][1] + be0.y;
        c0.z = acc[i][2] + be0.z; c0.w = acc[i][3] + be0.w;
        c1.x = acc[i][4] + be1.x; c1.y = acc[i][5] + be1.y;
        c1.z = acc[i][6] + be1.z; c1.w = acc[i][7] + be1.w;
        *(float4*)&z[rowoff]     = c0;
        *(float4*)&z[rowoff + 4] = c1;
    }
}

__global__ __launch_bounds__(256) void topk_kernel(
    float* __restrict__ z, float* __restrict__ tv, int* __restrict__ ti)
{
    const int row = blockIdx.x;
    float* zr = z + (size_t)row * NS;
    const int t = threadIdx.x;

    __shared__ unsigned hist[256];
    __shared__ unsigned s_prefix, s_pmask;
    __shared__ int s_need;
    __shared__ int eqidx[128];
    __shared__ int eqcnt, outcnt;
    __shared__ float osv[K];
    __shared__ int   osi[K];

    if (t == 0) { s_prefix = 0u; s_pmask = 0u; s_need = K; eqcnt = 0; outcnt = 0; }
    __syncthreads();

    for (int shift = 24; shift >= 0; shift -= 8) {
        hist[t] = 0u;
        __syncthreads();
        const unsigned prefix = s_prefix, pmask = s_pmask;
        for (int i = t; i < NS; i += 256) {
            unsigned u = fkey(zr[i]);
            if ((u & pmask) == prefix) atomicAdd(&hist[(u >> shift) & 255u], 1u);
        }
        __syncthreads();
        if (t == 0) {
            int need = s_need;
            unsigned cum = 0; int sel = 0;
            for (int b = 255; b >= 0; --b) {
                if (cum + hist[b] >= (unsigned)need) { sel = b; break; }
                cum += hist[b];
            }
            s_need   = need - (int)cum;
            s_prefix = prefix | ((unsigned)sel << shift);
            s_pmask  = pmask | (0xFFu << shift);
        }
        __syncthreads();
    }

    const unsigned T = s_prefix;
    const int need = s_need;

    for (int i = t; i < NS; i += 256) {
        if (fkey(zr[i]) == T) {
            int p = atomicAdd(&eqcnt, 1);
            if (p < 128) eqidx[p] = i;
        }
    }
    __syncthreads();
    if (t == 0) {
        int nn = eqcnt < 128 ? eqcnt : 128;
        int lim = need < nn ? need : nn;
        for (int a = 0; a < lim; ++a) {
            int mi = a;
            for (int b = a + 1; b < nn; ++b) if (eqidx[b] < eqidx[mi]) mi = b;
            int tmp = eqidx[a]; eqidx[a] = eqidx[mi]; eqidx[mi] = tmp;
        }
    }
    __syncthreads();

    for (int i = t; i < NS; i += 256) {
        const float v = zr[i];
        const unsigned u = fkey(v);
        bool take = (u > T);
        if (u == T) {
            for (int a = 0; a < need; ++a) if (eqidx[a] == i) { take = true; break; }
        }
        if (take) {
            int p = atomicAdd(&outcnt, 1);
            if (p < K) { osv[p] = v; osi[p] = i; }
        } else {
            zr[i] = 0.0f;
        }
    }
    __syncthreads();

    if (tv != nullptr && t < K) {
        const int   myi = osi[t];
        const float myv = osv[t];
        int r = 0;
        #pragma unroll 8
        for (int j = 0; j < K; ++j) r += (osi[j] < myi);
        tv[(size_t)row * K + r] = myv;
        ti[(size_t)row * K + r] = myi;
    }
}

__global__ __launch_bounds__(256) void decode_nt(
    const float* __restrict__ tv, const int* __restrict__ ti,
    const float* __restrict__ Wd, const float* __restrict__ bd,
    float* __restrict__ recon)
{
    const int row = blockIdx.x;
    const int t = threadIdx.x;
    __shared__ float sv[K];
    __shared__ int   si[K];
    if (t < K) { sv[t] = tv[(size_t)row * K + t]; si[t] = ti[(size_t)row * K + t]; }
    __syncthreads();
    float a0 = bd[t], a1 = bd[t + 256], a2 = bd[t + 512];
    for (int k = 0; k < K; ++k) {
        const float v = sv[k];
        const int s = si[k];
        a0 = fmaf(v, Wd[(size_t)t * NS + s],         a0);
        a1 = fmaf(v, Wd[(size_t)(t + 256) * NS + s], a1);
        a2 = fmaf(v, Wd[(size_t)(t + 512) * NS + s], a2);
    }
    float* rr = recon + (size_t)row * DM;
    rr[t] = a0; rr[t + 256] = a1; rr[t + 512] = a2;
}

__global__ __launch_bounds__(256) void decode_scan(
    const float* __restrict__ z, const float* __restrict__ Wd,
    const float* __restrict__ bd, float* __restrict__ recon)
{
    constexpr int CAP = 96;
    const int row = blockIdx.x;
    const int t = threadIdx.x;
    __shared__ float sv[CAP], sv2[CAP];
    __shared__ int   si[CAP], si2[CAP];
    __shared__ int cnt;
    if (t == 0) cnt = 0;
    __syncthreads();
    const float* zr = z + (size_t)row * NS;
    for (int i = t; i < NS; i += 256) {
        float v = zr[i];
        if (v != 0.0f) { int p = atomicAdd(&cnt, 1); if (p < CAP) { sv[p] = v; si[p] = i; } }
    }
    __syncthreads();
    const int n = cnt < CAP ? cnt : CAP;
    if (t < n) {
        int myi = si[t]; int r = 0;
        for (int j = 0; j < n; ++j) r += (si[j] < myi);
        sv2[r] = sv[t]; si2[r] = myi;
    }
    __syncthreads();
    float a0 = bd[t], a1 = bd[t + 256], a2 = bd[t + 512];
    for (int k = 0; k < n; ++k) {
        const float v = sv2[k];
        const int s = si2[k];
        a0 = fmaf(v, Wd[(size_t)t * NS + s],         a0);
        a1 = fmaf(v, Wd[(size_t)(t + 256) * NS + s], a1);
        a2 = fmaf(v, Wd[(size_t)(t + 512) * NS + s], a2);
    }
    float* rr = recon + (size_t)row * DM;
    rr[t] = a0; rr[t + 256] = a1; rr[t + 512] = a2;
}

// ===================== launch =====================
extern "C" void kernel_launch(void* const* d_in, const int* in_sizes, int n_in,
                              void* d_out, int out_size, void* d_ws, size_t ws_size,
                              hipStream_t stream) {
    const float* x  = (const float*)d_in[0];
    const float* We = (const float*)d_in[1];
    const float* be = (const float*)d_in[2];
    const float* Wd = (const float*)d_in[3];
    const float* bd = (const float*)d_in[4];
    const float* bp = (const float*)d_in[5];

    float* recon = (float*)d_out;                       // [8192][768]
    float* zs    = recon + (size_t)NB * DM;             // [8192][24576]

    const size_t szAh = (size_t)NB * DM * 2;            // 12.6 MB
    const size_t szBh = (size_t)NS * DM * 2;            // 37.7 MB
    const size_t szWT = (size_t)NS * DM * 4;            // 75.5 MB
    const size_t szTV = (size_t)NB * K * 4;             // 2 MB
    const size_t szTI = (size_t)NB * K * 4;             // 2 MB
    const size_t szFL = (size_t)NB * 4;                 // 32 KB
    const size_t need_fast = szAh + szBh + szWT + szTV + szTI + szFL;  // ~130 MB

    if (ws_size >= need_fast) {
        char* p = (char*)d_ws;
        short* Ah = (short*)p;           p += szAh;
        short* Bh = (short*)p;           p += szBh;
        float* WT = (float*)p;           p += szWT;
        float* tv = (float*)p;           p += szTV;
        int*   ti = (int*)p;             p += szTI;
        int*   fl = (int*)p;

        prep_bfA<<<NB * (DM / 4) / 256, 256, 0, stream>>>(x, bp, Ah);
        prep_bfB<<<NS * (DM / 4) / 256, 256, 0, stream>>>(We, Bh);
        encode_bf16<<<dim3(NS / 128, NB / 128), 256, 0, stream>>>(Ah, Bh, be, zs);
        transpose_wdec<<<dim3(NS / 32, DM / 32), 256, 0, stream>>>(Wd, WT);
        topk_fast<<<NB, 256, 0, stream>>>(zs, x, bp, We, be, tv, ti, fl);
        topk_fallback<<<NB, 256, 0, stream>>>(zs, x, bp, We, be, tv, ti, fl);
        decode_t<<<NB, 256, 0, stream>>>(tv, ti, WT, bd, recon);
    } else {
        const size_t need_small = szTV + szTI;
        const size_t need_big   = need_small + szWT;
        float* tv = (float*)d_ws;
        int*   ti = (int*)((char*)d_ws + szTV);
        float* WT = (float*)((char*)d_ws + need_small);

        dim3 gg(NS / BN, NB / BM);
        encode_gemm<<<gg, 256, 0, stream>>>(x, We, be, bp, zs);

        if (ws_size >= need_big) {
            transpose_wdec<<<dim3(NS / 32, DM / 32), 256, 0, stream>>>(Wd, WT);
            topk_kernel<<<NB, 256, 0, stream>>>(zs, tv, ti);
            decode_t<<<NB, 256, 0, stream>>>(tv, ti, WT, bd, recon);
        } else if (ws_size >= need_small) {
            topk_kernel<<<NB, 256, 0, stream>>>(zs, tv, ti);
            decode_nt<<<NB, 256, 0, stream>>>(tv, ti, Wd, bd, recon);
        } else {
            topk_kernel<<<NB, 256, 0, stream>>>(zs, nullptr, nullptr);
            decode_scan<<<NB, 256, 0, stream>>>(zs, Wd, bd, recon);
        }
    }
}